// Round 1
// baseline (386.235 us; speedup 1.0000x reference)
//
#include <hip/hip_runtime.h>
#include <hip/hip_bf16.h>
#include <stdint.h>

typedef __attribute__((ext_vector_type(4))) float f32x4;
typedef __attribute__((ext_vector_type(8))) short bf16x8;

#define BM 128
#define BN 128
#define BK 64

__device__ inline void gload_lds16(const void* g, void* l) {
    __builtin_amdgcn_global_load_lds(
        (const __attribute__((address_space(1))) void*)g,
        (__attribute__((address_space(3))) void*)l, 16, 0, 0);
}

// Convert features fp32 [16384][2144] -> bf16 [16384][2176] (zero padded cols 2144..2175)
__global__ __launch_bounds__(256) void cvt_feat(const float* __restrict__ in,
                                                __hip_bfloat16* __restrict__ out) {
    int i = blockIdx.x * 256 + threadIdx.x;        // one 8-element chunk each
    const int CH = 16384 * 272;                    // 2176/8 = 272 chunks per row
    if (i >= CH) return;
    int r = i / 272, c8 = (i % 272) * 8;
    __hip_bfloat16 tmp[8];
    if (c8 < 2144) {
        const float4* p = (const float4*)(in + (size_t)r * 2144 + c8);
        float4 x0 = p[0], x1 = p[1];
        tmp[0] = __float2bfloat16(x0.x); tmp[1] = __float2bfloat16(x0.y);
        tmp[2] = __float2bfloat16(x0.z); tmp[3] = __float2bfloat16(x0.w);
        tmp[4] = __float2bfloat16(x1.x); tmp[5] = __float2bfloat16(x1.y);
        tmp[6] = __float2bfloat16(x1.z); tmp[7] = __float2bfloat16(x1.w);
    } else {
        #pragma unroll
        for (int j = 0; j < 8; j++) tmp[j] = __float2bfloat16(0.f);
    }
    *(bf16x8*)&out[(size_t)r * 2176 + c8] = *(const bf16x8*)tmp;
}

// WT[n][k] = bf16(W[k][n]), zero-padded k in [K, KP)
__global__ __launch_bounds__(256) void cvt_wt(const float* __restrict__ W,
                                              __hip_bfloat16* __restrict__ WT,
                                              int K, int N, int KP) {
    int idx = blockIdx.x * 256 + threadIdx.x;
    if (idx >= N * KP) return;
    int n = idx / KP, k = idx % KP;
    WT[idx] = (k < K) ? __float2bfloat16(W[(size_t)k * N + n]) : __float2bfloat16(0.f);
}

// C[M][N] = A[M][K] (row stride lda) @ Bt[N][K]^T  + bias + residual, optional leaky->bf16 out
// RES_MODE: 0 none, 1 full res[M][N], 2 broadcast res[row>>5][N]
template<int RES_MODE, bool OUT_BF16, bool OUT_F32>
__global__ __launch_bounds__(256)
void gemm_bt(const __hip_bfloat16* __restrict__ A, int lda,
             const __hip_bfloat16* __restrict__ Bt,
             const float* __restrict__ bias,
             const float* __restrict__ res,
             __hip_bfloat16* __restrict__ outb,
             float* __restrict__ outf,
             int M, int N, int K)
{
    __shared__ __hip_bfloat16 lA[BM * BK];
    __shared__ __hip_bfloat16 lB[BN * BK];

    const int t    = threadIdx.x;
    const int lane = t & 63;
    const int wv   = t >> 6;           // 4 waves
    const int wr   = wv >> 1, wc = wv & 1;

    const int row0 = blockIdx.y * BM;
    const int col0 = blockIdx.x * BN;

    // staging: thread t loads 16B; covers [32 rows x 64 cols] per issue, 4 issues
    const int srow = t >> 3;           // 0..31
    const int scol = (t & 7) * 8;      // 0..56

    f32x4 acc[4][4];
    #pragma unroll
    for (int i = 0; i < 4; i++)
        #pragma unroll
        for (int j = 0; j < 4; j++)
            acc[i][j] = f32x4{0.f, 0.f, 0.f, 0.f};

    const int lrow = lane & 15;
    const int lk   = (lane >> 4) * 8;

    for (int kt = 0; kt < K; kt += BK) {
        #pragma unroll
        for (int is = 0; is < 4; is++) {
            const __hip_bfloat16* ga = A + (size_t)(row0 + srow + is * 32) * lda + kt + scol;
            gload_lds16(ga, lA + is * 2048 + wv * 512);
            const __hip_bfloat16* gb = Bt + (size_t)(col0 + srow + is * 32) * K + kt + scol;
            gload_lds16(gb, lB + is * 2048 + wv * 512);
        }
        __syncthreads();

        #pragma unroll
        for (int kk = 0; kk < BK; kk += 32) {
            bf16x8 af[4], bg[4];
            #pragma unroll
            for (int i = 0; i < 4; i++) {
                af[i] = *(const bf16x8*)&lA[(wr * 64 + i * 16 + lrow) * BK + kk + lk];
                bg[i] = *(const bf16x8*)&lB[(wc * 64 + i * 16 + lrow) * BK + kk + lk];
            }
            #pragma unroll
            for (int i = 0; i < 4; i++)
                #pragma unroll
                for (int j = 0; j < 4; j++)
                    acc[i][j] = __builtin_amdgcn_mfma_f32_16x16x32_bf16(af[i], bg[j], acc[i][j], 0, 0, 0);
        }
        __syncthreads();
    }

    // epilogue: C/D layout col=lane&15, row=(lane>>4)*4+reg
    #pragma unroll
    for (int j = 0; j < 4; j++) {
        const int col = col0 + wc * 64 + j * 16 + lrow;
        const float bv = bias ? bias[col] : 0.f;
        #pragma unroll
        for (int i = 0; i < 4; i++) {
            const int rbase = row0 + wr * 64 + i * 16 + (lane >> 4) * 4;
            #pragma unroll
            for (int r = 0; r < 4; r++) {
                const int row = rbase + r;
                float v = acc[i][j][r] + bv;
                if (RES_MODE == 1) v += res[(size_t)row * N + col];
                if (RES_MODE == 2) v += res[(size_t)(row >> 5) * N + col];
                if (OUT_F32) outf[(size_t)row * N + col] = v;
                if (OUT_BF16) {
                    float lv = v >= 0.f ? v : 0.01f * v;
                    outb[(size_t)row * N + col] = __float2bfloat16(lv);
                }
            }
        }
    }
}

// out[row] = leaky(h[row]) @ Wd + bd + [0,0,1], fp32, one wave per row
__global__ __launch_bounds__(256)
void final_head(const float* __restrict__ h, const float* __restrict__ Wd,
                const float* __restrict__ bd, float* __restrict__ out)
{
    int row  = blockIdx.x * 4 + (threadIdx.x >> 6);
    int lane = threadIdx.x & 63;
    const float* hr = h + (size_t)row * 512;
    float s0 = 0.f, s1 = 0.f, s2 = 0.f;
    #pragma unroll
    for (int j = 0; j < 8; j++) {
        int k = j * 64 + lane;
        float v = hr[k];
        v = v >= 0.f ? v : 0.01f * v;
        s0 += v * Wd[k * 3 + 0];
        s1 += v * Wd[k * 3 + 1];
        s2 += v * Wd[k * 3 + 2];
    }
    #pragma unroll
    for (int off = 32; off > 0; off >>= 1) {
        s0 += __shfl_down(s0, off);
        s1 += __shfl_down(s1, off);
        s2 += __shfl_down(s2, off);
    }
    if (lane == 0) {
        out[row * 3 + 0] = s0 + bd[0];
        out[row * 3 + 1] = s1 + bd[1];
        out[row * 3 + 2] = s2 + bd[2] + 1.0f;
    }
}

extern "C" void kernel_launch(void* const* d_in, const int* in_sizes, int n_in,
                              void* d_out, int out_size, void* d_ws, size_t ws_size,
                              hipStream_t stream)
{
    const float* features = (const float*)d_in[0];
    const float* We  = (const float*)d_in[1];
    const float* be  = (const float*)d_in[2];
    const float* W1a = (const float*)d_in[3];
    const float* b1a = (const float*)d_in[4];
    const float* W1b = (const float*)d_in[5];
    const float* b1b = (const float*)d_in[6];
    const float* W2a = (const float*)d_in[7];
    const float* b2a = (const float*)d_in[8];
    const float* W2b = (const float*)d_in[9];
    const float* b2b = (const float*)d_in[10];
    const float* Wd  = (const float*)d_in[11];
    const float* bd  = (const float*)d_in[12];
    float* out = (float*)d_out;

    char* ws = (char*)d_ws;
    size_t off = 0;
    auto alloc = [&](size_t bytes) -> char* {
        char* p = ws + off;
        off += (bytes + 255) & ~(size_t)255;
        return p;
    };
    __hip_bfloat16* featbf = (__hip_bfloat16*)alloc(16384ull * 2176 * 2); // padded K
    __hip_bfloat16* WeTt   = (__hip_bfloat16*)alloc(1024ull * 2176 * 2);
    __hip_bfloat16* WeTb   = (__hip_bfloat16*)alloc(1024ull * 2176 * 2);
    __hip_bfloat16* W1aT   = (__hip_bfloat16*)alloc(1024ull * 1024 * 2);
    __hip_bfloat16* W1bT   = (__hip_bfloat16*)alloc(512ull * 1024 * 2);
    __hip_bfloat16* W2aT   = (__hip_bfloat16*)alloc(512ull * 512 * 2);
    __hip_bfloat16* W2bT   = (__hip_bfloat16*)alloc(512ull * 512 * 2);
    float* eanchor         = (float*)alloc(512ull * 1024 * 4);
    char* bufA             = alloc(16384ull * 1024 * 2);   // act1 / act3 / hsum
    char* bufB             = alloc(16384ull * 1024 * 2);   // act2 / act4
    float* h1              = (float*)alloc(16384ull * 512 * 4);

    __hip_bfloat16* act1 = (__hip_bfloat16*)bufA;
    __hip_bfloat16* act2 = (__hip_bfloat16*)bufB;
    __hip_bfloat16* act3 = (__hip_bfloat16*)bufA;
    __hip_bfloat16* act4 = (__hip_bfloat16*)bufB;
    float*          hsum = (float*)bufA;

    // ---- converts ----
    cvt_feat<<<(16384 * 272 + 255) / 256, 256, 0, stream>>>(features, featbf);
    cvt_wt<<<(1024 * 2176 + 255) / 256, 256, 0, stream>>>(We,              WeTt, 2144, 1024, 2176);
    cvt_wt<<<(1024 * 2176 + 255) / 256, 256, 0, stream>>>(We + 2144 * 1024, WeTb, 2144, 1024, 2176);
    cvt_wt<<<(1024 * 1024 + 255) / 256, 256, 0, stream>>>(W1a, W1aT, 1024, 1024, 1024);
    cvt_wt<<<(512 * 1024 + 255) / 256, 256, 0, stream>>>(W1b, W1bT, 1024, 512, 1024);
    cvt_wt<<<(512 * 512 + 255) / 256, 256, 0, stream>>>(W2a, W2aT, 512, 512, 512);
    cvt_wt<<<(512 * 512 + 255) / 256, 256, 0, stream>>>(W2b, W2bT, 512, 512, 512);

    // ---- anchor GEMM: eanchor[b][n] = feat_row(b*32) @ We[2144:,:] + be ----
    gemm_bt<0, false, true><<<dim3(8, 4), 256, 0, stream>>>(
        featbf, 32 * 2176, WeTb, be, nullptr, nullptr, eanchor, 512, 1024, 2176);

    // ---- L1: act1 = bf16(leaky(feat @ We[:2144,:] + eanchor_bcast)) ----
    gemm_bt<2, true, false><<<dim3(8, 128), 256, 0, stream>>>(
        featbf, 2176, WeTt, nullptr, eanchor, act1, nullptr, 16384, 1024, 2176);

    // ---- L2: act2 = bf16(leaky(act1 @ W1a + b1a)) ----
    gemm_bt<0, true, false><<<dim3(8, 128), 256, 0, stream>>>(
        act1, 1024, W1aT, b1a, nullptr, act2, nullptr, 16384, 1024, 1024);

    // ---- L3: h1 = act2 @ W1b + b1b (fp32), act3 = bf16(leaky(h1)) ----
    gemm_bt<0, true, true><<<dim3(4, 128), 256, 0, stream>>>(
        act2, 1024, W1bT, b1b, nullptr, act3, h1, 16384, 512, 1024);

    // ---- L4: act4 = bf16(leaky(act3 @ W2a + b2a)) ----
    gemm_bt<0, true, false><<<dim3(4, 128), 256, 0, stream>>>(
        act3, 512, W2aT, b2a, nullptr, act4, nullptr, 16384, 512, 512);

    // ---- L5: hsum = act4 @ W2b + b2b + h1 (fp32) ----
    gemm_bt<1, false, true><<<dim3(4, 128), 256, 0, stream>>>(
        act4, 512, W2bT, b2b, h1, nullptr, hsum, 16384, 512, 512);

    // ---- head: out = leaky(hsum) @ Wd + bd + [0,0,1] ----
    final_head<<<4096, 256, 0, stream>>>(hsum, Wd, bd, out);
}

// Round 2
// 359.550 us; speedup vs baseline: 1.0742x; 1.0742x over previous
//
#include <hip/hip_runtime.h>
#include <hip/hip_bf16.h>
#include <stdint.h>

typedef __attribute__((ext_vector_type(4))) float f32x4;
typedef __attribute__((ext_vector_type(8))) short bf16x8;

#define BM 128
#define BN 128
#define BK 64

__device__ inline void gload_lds16(const void* g, void* l) {
    __builtin_amdgcn_global_load_lds(
        (const __attribute__((address_space(1))) void*)g,
        (__attribute__((address_space(3))) void*)l, 16, 0, 0);
}

// bijective XCD swizzle (m204): chunk the 1-D grid so each XCD gets a
// contiguous range of workgroup ids (per-XCD L2 locality).
__device__ inline int xcd_swizzle(int orig, int nwg) {
    int q = nwg >> 3, r = nwg & 7;
    int xcd = orig & 7, idx = orig >> 3;
    int base = (xcd < r) ? xcd * (q + 1) : r * (q + 1) + (xcd - r) * q;
    return base + idx;
}

// Convert features fp32 [16384][2144] -> bf16 [16384][2176] (zero padded cols 2144..2175)
__global__ __launch_bounds__(256) void cvt_feat(const float* __restrict__ in,
                                                __hip_bfloat16* __restrict__ out) {
    int i = blockIdx.x * 256 + threadIdx.x;        // one 8-element chunk each
    const int CH = 16384 * 272;                    // 2176/8 = 272 chunks per row
    if (i >= CH) return;
    int r = i / 272, c8 = (i % 272) * 8;
    __hip_bfloat16 tmp[8];
    if (c8 < 2144) {
        const float4* p = (const float4*)(in + (size_t)r * 2144 + c8);
        float4 x0 = p[0], x1 = p[1];
        tmp[0] = __float2bfloat16(x0.x); tmp[1] = __float2bfloat16(x0.y);
        tmp[2] = __float2bfloat16(x0.z); tmp[3] = __float2bfloat16(x0.w);
        tmp[4] = __float2bfloat16(x1.x); tmp[5] = __float2bfloat16(x1.y);
        tmp[6] = __float2bfloat16(x1.z); tmp[7] = __float2bfloat16(x1.w);
    } else {
        #pragma unroll
        for (int j = 0; j < 8; j++) tmp[j] = __float2bfloat16(0.f);
    }
    *(bf16x8*)&out[(size_t)r * 2176 + c8] = *(const bf16x8*)tmp;
}

// WT[n][k] = bf16(W[k][n]), zero-padded k in [K, KP)
__global__ __launch_bounds__(256) void cvt_wt(const float* __restrict__ W,
                                              __hip_bfloat16* __restrict__ WT,
                                              int K, int N, int KP) {
    int idx = blockIdx.x * 256 + threadIdx.x;
    if (idx >= N * KP) return;
    int n = idx / KP, k = idx % KP;
    WT[idx] = (k < K) ? __float2bfloat16(W[(size_t)k * N + n]) : __float2bfloat16(0.f);
}

// C[M][N] = A[M][K] (row stride lda) @ Bt[N][K]^T  + bias + residual, optional leaky->bf16 out
// RES_MODE: 0 none, 1 full res[M][N], 2 broadcast res[row>>5][N]
// Grid: x = 1-D block id (swizzled), y = split-K index (partials to outf + split*M*N,
//       pass bias=nullptr and reduce separately when gridDim.y > 1).
template<int RES_MODE, bool OUT_BF16, bool OUT_F32>
__global__ __launch_bounds__(256)
void gemm_bt(const __hip_bfloat16* __restrict__ A, int lda,
             const __hip_bfloat16* __restrict__ Bt,
             const float* __restrict__ bias,
             const float* __restrict__ res,
             __hip_bfloat16* __restrict__ outb,
             float* __restrict__ outf,
             int M, int N, int K, int gx)
{
    __shared__ __hip_bfloat16 lA[BM * BK];
    __shared__ __hip_bfloat16 lB[BN * BK];

    const int nwg  = gridDim.x;
    const int wgid = xcd_swizzle(blockIdx.x, nwg);
    const int by   = wgid / gx;
    const int bx   = wgid - by * gx;          // col fastest within an XCD chunk

    const int t    = threadIdx.x;
    const int lane = t & 63;
    const int wv   = t >> 6;           // 4 waves
    const int wr   = wv >> 1, wc = wv & 1;

    const int row0 = by * BM;
    const int col0 = bx * BN;

    // split-K range (uniform: gridDim.y==1 -> full K)
    const int NT = K / BK;
    const int split = blockIdx.y;
    const int kb = (split * NT) / gridDim.y;
    const int ke = ((split + 1) * NT) / gridDim.y;
    if (OUT_F32 && gridDim.y > 1) outf += (size_t)split * M * N;

    // staging: thread t loads 16B; covers [32 rows x 64 cols] per issue, 4 issues
    const int srow = t >> 3;           // 0..31
    const int scol = (t & 7) * 8;      // 0..56

    f32x4 acc[4][4];
    #pragma unroll
    for (int i = 0; i < 4; i++)
        #pragma unroll
        for (int j = 0; j < 4; j++)
            acc[i][j] = f32x4{0.f, 0.f, 0.f, 0.f};

    const int lrow = lane & 15;
    const int lk   = (lane >> 4) * 8;

    for (int kt = kb * BK; kt < ke * BK; kt += BK) {
        #pragma unroll
        for (int is = 0; is < 4; is++) {
            const __hip_bfloat16* ga = A + (size_t)(row0 + srow + is * 32) * lda + kt + scol;
            gload_lds16(ga, lA + is * 2048 + wv * 512);
            const __hip_bfloat16* gb = Bt + (size_t)(col0 + srow + is * 32) * K + kt + scol;
            gload_lds16(gb, lB + is * 2048 + wv * 512);
        }
        __syncthreads();

        #pragma unroll
        for (int kk = 0; kk < BK; kk += 32) {
            bf16x8 af[4], bg[4];
            #pragma unroll
            for (int i = 0; i < 4; i++) {
                af[i] = *(const bf16x8*)&lA[(wr * 64 + i * 16 + lrow) * BK + kk + lk];
                bg[i] = *(const bf16x8*)&lB[(wc * 64 + i * 16 + lrow) * BK + kk + lk];
            }
            #pragma unroll
            for (int i = 0; i < 4; i++)
                #pragma unroll
                for (int j = 0; j < 4; j++)
                    acc[i][j] = __builtin_amdgcn_mfma_f32_16x16x32_bf16(af[i], bg[j], acc[i][j], 0, 0, 0);
        }
        __syncthreads();
    }

    // epilogue: C/D layout col=lane&15, row=(lane>>4)*4+reg
    #pragma unroll
    for (int j = 0; j < 4; j++) {
        const int col = col0 + wc * 64 + j * 16 + lrow;
        const float bv = bias ? bias[col] : 0.f;
        #pragma unroll
        for (int i = 0; i < 4; i++) {
            const int rbase = row0 + wr * 64 + i * 16 + (lane >> 4) * 4;
            #pragma unroll
            for (int r = 0; r < 4; r++) {
                const int row = rbase + r;
                float v = acc[i][j][r] + bv;
                if (RES_MODE == 1) v += res[(size_t)row * N + col];
                if (RES_MODE == 2) v += res[(size_t)(row >> 5) * N + col];
                if (OUT_F32) outf[(size_t)row * N + col] = v;
                if (OUT_BF16) {
                    float lv = v >= 0.f ? v : 0.01f * v;
                    outb[(size_t)row * N + col] = __float2bfloat16(lv);
                }
            }
        }
    }
}

// eanchor = sum of 4 split-K partials + be
__global__ __launch_bounds__(256)
void anchor_reduce(const float* __restrict__ part, const float* __restrict__ be,
                   float* __restrict__ out) {
    int i = blockIdx.x * 256 + threadIdx.x;     // 512*1024 elements
    if (i >= 512 * 1024) return;
    const int S = 512 * 1024;
    int col = i & 1023;
    out[i] = part[i] + part[i + S] + part[i + 2 * S] + part[i + 3 * S] + be[col];
}

// out[row] = leaky(h[row]) @ Wd + bd + [0,0,1], fp32, one wave per row
__global__ __launch_bounds__(256)
void final_head(const float* __restrict__ h, const float* __restrict__ Wd,
                const float* __restrict__ bd, float* __restrict__ out)
{
    int row  = blockIdx.x * 4 + (threadIdx.x >> 6);
    int lane = threadIdx.x & 63;
    const float* hr = h + (size_t)row * 512;
    float s0 = 0.f, s1 = 0.f, s2 = 0.f;
    #pragma unroll
    for (int j = 0; j < 8; j++) {
        int k = j * 64 + lane;
        float v = hr[k];
        v = v >= 0.f ? v : 0.01f * v;
        s0 += v * Wd[k * 3 + 0];
        s1 += v * Wd[k * 3 + 1];
        s2 += v * Wd[k * 3 + 2];
    }
    #pragma unroll
    for (int off = 32; off > 0; off >>= 1) {
        s0 += __shfl_down(s0, off);
        s1 += __shfl_down(s1, off);
        s2 += __shfl_down(s2, off);
    }
    if (lane == 0) {
        out[row * 3 + 0] = s0 + bd[0];
        out[row * 3 + 1] = s1 + bd[1];
        out[row * 3 + 2] = s2 + bd[2] + 1.0f;
    }
}

extern "C" void kernel_launch(void* const* d_in, const int* in_sizes, int n_in,
                              void* d_out, int out_size, void* d_ws, size_t ws_size,
                              hipStream_t stream)
{
    const float* features = (const float*)d_in[0];
    const float* We  = (const float*)d_in[1];
    const float* be  = (const float*)d_in[2];
    const float* W1a = (const float*)d_in[3];
    const float* b1a = (const float*)d_in[4];
    const float* W1b = (const float*)d_in[5];
    const float* b1b = (const float*)d_in[6];
    const float* W2a = (const float*)d_in[7];
    const float* b2a = (const float*)d_in[8];
    const float* W2b = (const float*)d_in[9];
    const float* b2b = (const float*)d_in[10];
    const float* Wd  = (const float*)d_in[11];
    const float* bd  = (const float*)d_in[12];
    float* out = (float*)d_out;

    char* ws = (char*)d_ws;
    size_t off = 0;
    auto alloc = [&](size_t bytes) -> char* {
        char* p = ws + off;
        off += (bytes + 255) & ~(size_t)255;
        return p;
    };
    __hip_bfloat16* featbf = (__hip_bfloat16*)alloc(16384ull * 2176 * 2); // padded K
    __hip_bfloat16* WeTt   = (__hip_bfloat16*)alloc(1024ull * 2176 * 2);
    __hip_bfloat16* WeTb   = (__hip_bfloat16*)alloc(1024ull * 2176 * 2);
    __hip_bfloat16* W1aT   = (__hip_bfloat16*)alloc(1024ull * 1024 * 2);
    __hip_bfloat16* W1bT   = (__hip_bfloat16*)alloc(512ull * 1024 * 2);
    __hip_bfloat16* W2aT   = (__hip_bfloat16*)alloc(512ull * 512 * 2);
    __hip_bfloat16* W2bT   = (__hip_bfloat16*)alloc(512ull * 512 * 2);
    float* eanchor_part    = (float*)alloc(4ull * 512 * 1024 * 4);
    float* eanchor         = (float*)alloc(512ull * 1024 * 4);
    char* bufA             = alloc(16384ull * 1024 * 2);   // act1 / act3 / hsum
    char* bufB             = alloc(16384ull * 1024 * 2);   // act2 / act4
    float* h1              = (float*)alloc(16384ull * 512 * 4);

    __hip_bfloat16* act1 = (__hip_bfloat16*)bufA;
    __hip_bfloat16* act2 = (__hip_bfloat16*)bufB;
    __hip_bfloat16* act3 = (__hip_bfloat16*)bufA;
    __hip_bfloat16* act4 = (__hip_bfloat16*)bufB;
    float*          hsum = (float*)bufA;

    // ---- converts ----
    cvt_feat<<<(16384 * 272 + 255) / 256, 256, 0, stream>>>(features, featbf);
    cvt_wt<<<(1024 * 2176 + 255) / 256, 256, 0, stream>>>(We,              WeTt, 2144, 1024, 2176);
    cvt_wt<<<(1024 * 2176 + 255) / 256, 256, 0, stream>>>(We + 2144 * 1024, WeTb, 2144, 1024, 2176);
    cvt_wt<<<(1024 * 1024 + 255) / 256, 256, 0, stream>>>(W1a, W1aT, 1024, 1024, 1024);
    cvt_wt<<<(512 * 1024 + 255) / 256, 256, 0, stream>>>(W1b, W1bT, 1024, 512, 1024);
    cvt_wt<<<(512 * 512 + 255) / 256, 256, 0, stream>>>(W2a, W2aT, 512, 512, 512);
    cvt_wt<<<(512 * 512 + 255) / 256, 256, 0, stream>>>(W2b, W2bT, 512, 512, 512);

    // ---- anchor GEMM (split-K=4): partials[s] = feat_row(b*32) @ We[2144:,:] ----
    gemm_bt<0, false, true><<<dim3(32, 4), 256, 0, stream>>>(
        featbf, 32 * 2176, WeTb, nullptr, nullptr, nullptr, eanchor_part,
        512, 1024, 2176, 8);
    anchor_reduce<<<2048, 256, 0, stream>>>(eanchor_part, be, eanchor);

    // ---- L1: act1 = bf16(leaky(feat @ We[:2144,:] + eanchor_bcast)) ----
    gemm_bt<2, true, false><<<dim3(1024), 256, 0, stream>>>(
        featbf, 2176, WeTt, nullptr, eanchor, act1, nullptr, 16384, 1024, 2176, 8);

    // ---- L2: act2 = bf16(leaky(act1 @ W1a + b1a)) ----
    gemm_bt<0, true, false><<<dim3(1024), 256, 0, stream>>>(
        act1, 1024, W1aT, b1a, nullptr, act2, nullptr, 16384, 1024, 1024, 8);

    // ---- L3: h1 = act2 @ W1b + b1b (fp32), act3 = bf16(leaky(h1)) ----
    gemm_bt<0, true, true><<<dim3(512), 256, 0, stream>>>(
        act2, 1024, W1bT, b1b, nullptr, act3, h1, 16384, 512, 1024, 4);

    // ---- L4: act4 = bf16(leaky(act3 @ W2a + b2a)) ----
    gemm_bt<0, true, false><<<dim3(512), 256, 0, stream>>>(
        act3, 512, W2aT, b2a, nullptr, act4, nullptr, 16384, 512, 512, 4);

    // ---- L5: hsum = act4 @ W2b + b2b + h1 (fp32) ----
    gemm_bt<1, false, true><<<dim3(512), 256, 0, stream>>>(
        act4, 512, W2bT, b2b, h1, nullptr, hsum, 16384, 512, 512, 4);

    // ---- head: out = leaky(hsum) @ Wd + bd + [0,0,1] ----
    final_head<<<4096, 256, 0, stream>>>(hsum, Wd, bd, out);
}